// Round 7
// baseline (385.343 us; speedup 1.0000x reference)
//
#include <hip/hip_runtime.h>
#include <hip/hip_bf16.h>

// Attention: x[8,2048,1024] fp32, W_qkv[1024,3072] fp32, b_qkv[3072] fp32 -> out[8,2048,1024] fp32
// 256x256-tile bf16 GEMMs, r6 schedule (read-ahead 4-phase + SBAR0 pinning + counted vmcnt).
// Round-7 deltas:
//  (1) MFMA shape 16x16x32 -> 32x32x16: same FLOPs/LDS traffic/registers, HALF the MFMA
//      instructions; measured shape ceiling 2495 vs 2176 TF (m119) => ~15% issue headroom.
//  (2) p3 B-reload interleave: each bn frag is consumed by exactly one MFMA in phase q3, so
//      emit {mfma(bn[f]); ds_read bn[f]<-buf^1} pairs (WAR keeps order; sched_group_barrier
//      pins 1:1) -- removes the ~600cy/tile exposed LDS-port hole after MMQ(q3) without the
//      +32 VGPR a bn double-buffer would cost (we sit exactly at the 256-reg/wave wall).
// Fused softmax: QK^T epilogue writes E=exp(S) bf16 + atomic fp32 row sums; PV normalizes.

typedef __attribute__((ext_vector_type(8))) short bf16x8;
typedef __attribute__((ext_vector_type(4))) float f32x4;
typedef __attribute__((ext_vector_type(16))) float f32x16;
typedef __attribute__((ext_vector_type(8))) unsigned short u16x8;
typedef __attribute__((address_space(1))) const unsigned int gu32;
typedef __attribute__((address_space(3))) unsigned int lu32;

__device__ __forceinline__ unsigned short f2bf(float f) {
  union { float f; unsigned int u; } v; v.f = f;
  unsigned int r = v.u + 0x7fffu + ((v.u >> 16) & 1u);  // RNE
  return (unsigned short)(r >> 16);
}
__device__ __forceinline__ void cp16(const unsigned short* g, unsigned short* l) {
  __builtin_amdgcn_global_load_lds((gu32*)g, (lu32*)l, 16, 0, 0);
}

// ---- merged prep: x->xb bf16 (blocks 0..8191), W->Wt transpose (8192..8959), rowsum=0 (8960..9023)
__global__ __launch_bounds__(256) void prep(const float* __restrict__ x,
                                            unsigned short* __restrict__ xb,
                                            const float* __restrict__ W,
                                            unsigned short* __restrict__ Wt,
                                            float* __restrict__ rowsum) {
  __shared__ unsigned short tile[64][72];
  int bid = blockIdx.x, t = threadIdx.x;
  if (bid < 8192) {
    long i = ((long)bid * 256 + t) * 8;
    float4 a = *(const float4*)(x + i);
    float4 b = *(const float4*)(x + i + 4);
    u16x8 o;
    o[0] = f2bf(a.x); o[1] = f2bf(a.y); o[2] = f2bf(a.z); o[3] = f2bf(a.w);
    o[4] = f2bf(b.x); o[5] = f2bf(b.y); o[6] = f2bf(b.z); o[7] = f2bf(b.w);
    *(u16x8*)(xb + i) = o;
  } else if (bid < 8960) {
    int wb = bid - 8192;
    int fb = wb % 48, db = wb / 48;
#pragma unroll
    for (int it = 0; it < 4; it++) {
      int c = t + it * 256;
      int r = c >> 4, c4 = (c & 15) * 4;
      float4 v = *(const float4*)(W + (long)(db * 64 + r) * 3072 + fb * 64 + c4);
      tile[r][c4 + 0] = f2bf(v.x); tile[r][c4 + 1] = f2bf(v.y);
      tile[r][c4 + 2] = f2bf(v.z); tile[r][c4 + 3] = f2bf(v.w);
    }
    __syncthreads();
#pragma unroll
    for (int it = 0; it < 2; it++) {
      int c = t + it * 256;
      int r2 = c >> 3, k8 = (c & 7) * 8;
      u16x8 o;
#pragma unroll
      for (int j = 0; j < 8; j++) o[j] = tile[k8 + j][r2];
      *(u16x8*)(Wt + (long)(fb * 64 + r2) * 1024 + db * 64 + k8) = o;
    }
  } else {
    rowsum[(bid - 8960) * 256 + t] = 0.f;
  }
}

// ---- NT bf16 GEMM, 256x256 tile, BK=64, read-ahead 4-phase pipeline, 32x32x16 MFMA ----
// C[M,Ncols] = A[M,K]*B[Ncols,K]^T, K/64 a power of two (16 or 32 here).
// MODE 1: QKV epilogue: bf16(acc + bias[f]) -> Q,K row-major; V-blocks -> Vt[b][d][n] (LDS tr)
// MODE 3: E = bf16(exp(acc*scale)); fp32 row-sum partials atomicAdd'ed to rsum
// MODE 4: fp32 C = acc / rsum[row]  (PV -> out; fp32 stores are already full-line)
// SWZ: n-tile count; grid.x flattened: XCD-bijective remap then 4x4 super-tile decode.
template <int MODE, int SWZ>
__global__ __launch_bounds__(512, 2) void gemm256(
    const unsigned short* __restrict__ A, const unsigned short* __restrict__ B,
    float* __restrict__ C, const float* __restrict__ bias, int Ncols, int K, float scale,
    unsigned short* __restrict__ qp, unsigned short* __restrict__ kp,
    unsigned short* __restrict__ vp, float* __restrict__ rsum,
    long strA, long strB, long strC) {
  __shared__ __align__(16) unsigned short smem[4][256 * 64];  // [0..1]=A bufs, [2..3]=B bufs
  const int tid = threadIdx.x;
  const int lane = tid & 63, wave = tid >> 6;
  const int l32 = lane & 31, h5 = lane >> 5;
  const int lr = lane >> 3, lc = lane & 7;
  const int bz = blockIdx.z;
  int mt, nt;
  {
    int bid = blockIdx.x;
    const int nx = gridDim.x;                  // multiple of 8
    bid = (bid & 7) * (nx >> 3) + (bid >> 3);  // XCD-contiguous bijective remap
    int w = bid & 15, st = bid >> 4;
    constexpr int NSUP = (SWZ >= 4) ? (SWZ / 4) : 1;
    mt = (st / NSUP) * 4 + (w >> 2);
    nt = (st % NSUP) * 4 + (w & 3);
  }
  const long m0 = (long)mt * 256;
  const int n0 = nt * 256;
  const int wm128 = (wave >> 2) * 128;   // wave's 128-row A stripe
  const int wn64 = (wave & 3) * 64;      // wave's 64-row B stripe
  const int NT = K >> 6, mask = NT - 1;

  const unsigned short* __restrict__ Ab = A + (long)bz * strA;
  const unsigned short* __restrict__ Bb = B + (long)bz * strB;

  // staging sub-units (8 KB = 1 cp16/thread each):
  //   A units: 0={rows 0-63}, 1={128-191}, 2={64-127}, 3={192-255}
  //   B units: 0={0-31,64-95}, 1={128-159,192-223}, 2={32-63,96-127}, 3={160-191,224-255}
  unsigned int aSrc[4], bSrc[4];
  int aOff[4], bOff[4];
  {
    const int auL[4] = {0, 128, 64, 192}, auH[4] = {32, 160, 96, 224};
    const int buL[4] = {0, 128, 32, 160}, buH[4] = {64, 192, 96, 224};
    const bool wlo = wave < 4;
    const int w8 = (wave & 3) * 8;
    const int sc = (lc ^ lr) * 8;  // pre-swizzled global chunk (LDS stays linear)
#pragma unroll
    for (int u = 0; u < 4; u++) {
      int ra = (wlo ? auL[u] : auH[u]) + w8 + lr;
      int rb = (wlo ? buL[u] : buH[u]) + w8 + lr;
      aSrc[u] = (unsigned int)(((int)m0 + ra) * K + sc);
      bSrc[u] = (unsigned int)((n0 + rb) * K + sc);
      aOff[u] = ra * 64 + lc * 8;
      bOff[u] = rb * 64 + lc * 8;
    }
  }

#define SA(u, bb, tt) cp16(Ab + aSrc[u] + (tt) * 64, &smem[bb][aOff[u]])
#define SB(u, bb, tt) cp16(Bb + bSrc[u] + (tt) * 64, &smem[2 + (bb)][bOff[u]])

  // accumulators: 4 m-tiles x 2 n-tiles of 32x32 (16 f32/lane) = 128 regs
  f32x16 acc[4][2];
#pragma unroll
  for (int i = 0; i < 4; i++)
#pragma unroll
    for (int j = 0; j < 2; j++)
#pragma unroll
      for (int r = 0; r < 16; r++) acc[i][j][r] = 0.f;
  bf16x8 am[2][4];  // [regbuf][ks] - A m-tile double-buffer (32 regs)
  bf16x8 bn[2][4];  // [nt2][ks]    - full B stripe, 1 K-tile (32 regs)

  // A-frag lane layout (32x32x16): m = l32, k = ks*16 + h5*8 + j  => 16B global chunk ks*2+h5
  // LDS holds global chunk g at chunk slot g ^ (row&7).
#define RD_AQ(d, bb, mtq)                                                                   \
  {                                                                                         \
    int row_ = wm128 + (mtq) * 32 + l32;                                                    \
    int rx_ = row_ & 7;                                                                     \
    _Pragma("unroll") for (int ks = 0; ks < 4; ks++)                                        \
        am[d][ks] = *(const bf16x8*)(&smem[bb][row_ * 64 + (((ks * 2 + h5) ^ rx_) * 8)]);   \
  }
#define RD_BALL(bb)                                                                         \
  _Pragma("unroll") for (int nt2 = 0; nt2 < 2; nt2++) {                                     \
    int row_ = wn64 + nt2 * 32 + l32;                                                       \
    int rx_ = row_ & 7;                                                                     \
    _Pragma("unroll") for (int ks = 0; ks < 4; ks++)                                        \
        bn[nt2][ks] = *(const bf16x8*)(&smem[2 + (bb)][row_ * 64 + (((ks * 2 + h5) ^ rx_) * 8)]); \
  }
  // MFMA: m-tile mtq from regbuf d x both n-tiles (8 MFMA of 32x32x16)
#define MMQ(mtq, d)                                                                         \
  _Pragma("unroll") for (int nt2 = 0; nt2 < 2; nt2++)                                       \
      _Pragma("unroll") for (int ks = 0; ks < 4; ks++)                                      \
          acc[mtq][nt2] = __builtin_amdgcn_mfma_f32_32x32x16_bf16(                          \
              am[d][ks], bn[nt2][ks], acc[mtq][nt2], 0, 0, 0);
  // q3 variant: each bn frag has exactly one consumer here -> consume then reload from buf nb
  // (WAR keeps mfma before the overwriting ds_read; SGB pins the 1:1 interleave).
#define MMQ_BSWAP(mtq, d, nb)                                                               \
  _Pragma("unroll") for (int nt2 = 0; nt2 < 2; nt2++) {                                     \
    int row_ = wn64 + nt2 * 32 + l32;                                                       \
    int rx_ = row_ & 7;                                                                     \
    _Pragma("unroll") for (int ks = 0; ks < 4; ks++) {                                      \
      acc[mtq][nt2] = __builtin_amdgcn_mfma_f32_32x32x16_bf16(                              \
          am[d][ks], bn[nt2][ks], acc[mtq][nt2], 0, 0, 0);                                  \
      bn[nt2][ks] = *(const bf16x8*)(&smem[2 + (nb)][row_ * 64 + (((ks * 2 + h5) ^ rx_) * 8)]); \
      __builtin_amdgcn_sched_group_barrier(0x008, 1, 0);                                    \
      __builtin_amdgcn_sched_group_barrier(0x100, 1, 0);                                    \
    }                                                                                       \
  }
#define ABAR asm volatile("s_barrier" ::: "memory")
#define LGKM0 asm volatile("s_waitcnt lgkmcnt(0)" ::: "memory")
#define VMCNT4 asm volatile("s_waitcnt vmcnt(4)" ::: "memory")
#define PRIO1 __builtin_amdgcn_s_setprio(1)
#define PRIO0 __builtin_amdgcn_s_setprio(0)
#define SBAR0 __builtin_amdgcn_sched_barrier(0)

  // Phase = {LGKM0; read-ahead; ABAR; stage; [SBAR0] MFMA [SBAR0]}. Same WAR discipline as r6
  // (phase m-tile groups read the same row ranges as the old quarters). VMCNT4 @p2 pre-barrier:
  // tile t+1 fully landed before p3 reads buf^1. t2_ CLAMPED: tail junk re-reads last tile.
#define TILE(bb, tt)                                                                        \
  {                                                                                         \
    const int t2c_ = (tt) + 2;                                                              \
    const int t2_ = t2c_ > mask ? mask : t2c_;                                              \
    /* p0 */                                                                                \
    LGKM0; RD_AQ(1, bb, 1); ABAR;                                                           \
    SB(0, bb, t2_); SB(1, bb, t2_);                                                         \
    SBAR0; PRIO1; MMQ(0, 0); PRIO0; SBAR0;                                                  \
    /* p1 */                                                                                \
    LGKM0; RD_AQ(0, bb, 2); ABAR;                                                           \
    SA(0, bb, t2_); SA(1, bb, t2_);                                                         \
    SBAR0; PRIO1; MMQ(1, 1); PRIO0; SBAR0;                                                  \
    /* p2 */                                                                                \
    LGKM0; RD_AQ(1, bb, 3); VMCNT4; ABAR;                                                   \
    SB(2, bb, t2_); SB(3, bb, t2_);                                                         \
    SBAR0; PRIO1; MMQ(2, 0); PRIO0; SBAR0;                                                  \
    /* p3: MFMA q3 with B-reload interleave (reads buf^1's B during the MFMA stream) */     \
    LGKM0; RD_AQ(0, (bb) ^ 1, 0);                                                           \
    SBAR0; PRIO1; MMQ_BSWAP(3, 1, (bb) ^ 1); PRIO0; SBAR0;                                  \
    ABAR;                                                                                   \
    SA(2, bb, t2_); SA(3, bb, t2_);                                                         \
  }

  // prologue: stage tile0 + tile1 fully; land tile0 (all waves); read tile0's q0 + B
  SA(0, 0, 0); SA(1, 0, 0); SB(0, 0, 0); SB(1, 0, 0);
  SA(2, 0, 0); SA(3, 0, 0); SB(2, 0, 0); SB(3, 0, 0);
  SA(0, 1, 1); SA(1, 1, 1); SB(0, 1, 1); SB(1, 1, 1);
  SA(2, 1, 1); SA(3, 1, 1); SB(2, 1, 1); SB(3, 1, 1);
  asm volatile("s_waitcnt vmcnt(8)" ::: "memory");
  ABAR;
  RD_AQ(0, 0, 0);
  RD_BALL(0);

#pragma unroll 1
  for (int t = 0; t < NT; t += 2) {
    TILE(0, t);
    TILE(1, t + 1);
  }

  // 32x32 C/D layout: col = l32, row = (r&3) + 8*(r>>2) + 4*h5, r in [0,16)
  if (MODE == 1 || MODE == 3) {
    // ---- LDS-staged coalesced epilogue: 128KB LDS = one 256x256 bf16 C-tile ----
    asm volatile("s_waitcnt vmcnt(0)" ::: "memory");  // junk stages done writing LDS
    __syncthreads();
    unsigned short* Cs = &smem[0][0];  // row stride 512B, 16B-chunk XOR swizzle by (row&7)<<4
    if (MODE == 1) {
      float bv[2];
#pragma unroll
      for (int nt2 = 0; nt2 < 2; nt2++) bv[nt2] = bias[n0 + wn64 + nt2 * 32 + l32];
      const bool isV = (n0 >= 2048);  // V-blocks dump TRANSPOSED: LDS[row=d][col=n]
#pragma unroll
      for (int i = 0; i < 4; i++)
#pragma unroll
        for (int nt2 = 0; nt2 < 2; nt2++)
#pragma unroll
          for (int r = 0; r < 16; r++) {
            int rw = wm128 + i * 32 + (r & 3) + ((r >> 2) * 8) + 4 * h5;
            int cl = wn64 + nt2 * 32 + l32;
            unsigned short hv = f2bf(acc[i][nt2][r] + bv[nt2]);
            int row = isV ? cl : rw, col = isV ? rw : cl;
            *(unsigned short*)((char*)Cs + ((row * 512 + col * 2) ^ ((row & 7) << 4))) = hv;
          }
    } else {
      float* rs = rsum + bz * 2048;
#pragma unroll
      for (int i = 0; i < 4; i++)
#pragma unroll
        for (int r = 0; r < 16; r++) {
          int rw = wm128 + i * 32 + (r & 3) + ((r >> 2) * 8) + 4 * h5;
          float psum = 0.f;
#pragma unroll
          for (int nt2 = 0; nt2 < 2; nt2++) {
            float e = __expf(acc[i][nt2][r] * scale);
            psum += e;
            int col = wn64 + nt2 * 32 + l32;
            *(unsigned short*)((char*)Cs + ((rw * 512 + col * 2) ^ ((rw & 7) << 4))) = f2bf(e);
          }
          psum += __shfl_xor(psum, 1);
          psum += __shfl_xor(psum, 2);
          psum += __shfl_xor(psum, 4);
          psum += __shfl_xor(psum, 8);
          psum += __shfl_xor(psum, 16);
          if (l32 == 0) atomicAdd(rs + (m0 + rw), psum);
        }
    }
    __syncthreads();
    // write-out: 16 rounds x 256 rows, 512B contiguous per row (full lines, 16B/lane)
    const int rrow = tid >> 5, rchunk = tid & 31;
    unsigned short* dst;
    long rowstr, rowbase, colbase;
    if (MODE == 3) {
      dst = qp + (long)bz * strC;
      rowstr = Ncols; rowbase = m0; colbase = n0;
    } else if (n0 < 2048) {
      dst = (n0 < 1024) ? qp : kp;
      rowstr = 1024; rowbase = m0; colbase = n0 & 1023;
    } else {
      dst = vp;  // Vt[b][d][n]
      rowstr = 2048; rowbase = (m0 >> 11) * 1024 + (n0 - 2048); colbase = m0 & 2047;
    }
#pragma unroll
    for (int k = 0; k < 16; k++) {
      int row = k * 16 + rrow;
      u16x8 v = *(const u16x8*)((char*)Cs + ((row * 512 + rchunk * 16) ^ ((row & 7) << 4)));
      *(u16x8*)(dst + (rowbase + row) * rowstr + colbase + rchunk * 8) = v;
    }
  } else {
    float* Co = C + (long)bz * strC;
    const float* rs = rsum + bz * 2048;
#pragma unroll
    for (int i = 0; i < 4; i++)
#pragma unroll
      for (int r = 0; r < 16; r++) {
        long gm = m0 + wm128 + i * 32 + (r & 3) + ((r >> 2) * 8) + 4 * h5;
        float inv = 1.0f / rs[gm];
#pragma unroll
        for (int nt2 = 0; nt2 < 2; nt2++)
          Co[gm * Ncols + n0 + wn64 + nt2 * 32 + l32] = acc[i][nt2][r] * inv;
      }
  }
  // drain in-flight junk prefetches + junk ds_reads before block exit
  asm volatile("s_waitcnt vmcnt(0) lgkmcnt(0)" ::: "memory");
#undef SA
#undef SB
#undef RD_AQ
#undef RD_BALL
#undef MMQ
#undef MMQ_BSWAP
#undef TILE
#undef ABAR
#undef LGKM0
#undef VMCNT4
#undef PRIO1
#undef PRIO0
#undef SBAR0
}

extern "C" void kernel_launch(void* const* d_in, const int* in_sizes, int n_in,
                              void* d_out, int out_size, void* d_ws, size_t ws_size,
                              hipStream_t stream) {
  const float* x = (const float*)d_in[0];
  const float* W = (const float*)d_in[1];
  const float* bq = (const float*)d_in[2];
  float* out = (float*)d_out;
  char* ws = (char*)d_ws;
  const long MB = 1L << 20;
  // Persistent: Q 0-32, K 32-64, Vt 64-96.
  // Phase A scratch: xb 96-128, Wt 128-134 (dead after QKV).
  // Phase B scratch: E bf16 96-160 (overlaps dead xb/Wt). rowsum 160 MB (64 KB).
  unsigned short* Q  = (unsigned short*)(ws);
  unsigned short* Kb = (unsigned short*)(ws + 32 * MB);
  unsigned short* Vt = (unsigned short*)(ws + 64 * MB);
  unsigned short* xb = (unsigned short*)(ws + 96 * MB);
  unsigned short* Wt = (unsigned short*)(ws + 128 * MB);
  unsigned short* E  = (unsigned short*)(ws + 96 * MB);
  float* rowsum      = (float*)(ws + 160 * MB);  // 8*2048 fp32 = 64 KB

  prep<<<9024, 256, 0, stream>>>(x, xb, W, Wt, rowsum);
  // QKV: [16384,3072] = xb[16384,1024] @ Wt[3072,1024]^T -> Q,K row-major; V -> Vt (LDS tr)
  gemm256<1, 12><<<dim3(768, 1, 1), 512, 0, stream>>>(xb, Wt, nullptr, bq, 3072, 1024, 1.0f,
                                                      Q, Kb, Vt, nullptr, 0, 0, 0);
  // E = exp((Q K^T) * scale) bf16 + rowsum atomics
  gemm256<3, 8><<<dim3(64, 1, 8), 512, 0, stream>>>(Q, Kb, nullptr, nullptr, 2048, 1024,
                                                    0.03125f, E, nullptr, nullptr, rowsum,
                                                    2048L * 1024, 2048L * 1024, 2048L * 2048);
  // out = (E @ Vt^T) / rowsum, fp32
  gemm256<4, 4><<<dim3(32, 1, 8), 512, 0, stream>>>(E, Vt, out, nullptr, 1024, 2048, 1.0f,
                                                    nullptr, nullptr, nullptr, rowsum,
                                                    2048L * 2048, 1024L * 2048, 2048L * 1024);
}

// Round 8
// 366.791 us; speedup vs baseline: 1.0506x; 1.0506x over previous
//
#include <hip/hip_runtime.h>
#include <hip/hip_bf16.h>

// Attention: x[8,2048,1024] fp32, W_qkv[1024,3072] fp32, b_qkv[3072] fp32 -> out[8,2048,1024] fp32
// 256x256-tile bf16 GEMMs, r6 schedule: read-ahead 4-phase + SBAR0-pinned MFMA clusters +
// counted vmcnt + LDS-staged coalesced epilogue. 16x16x32 MFMA (r7's 32x32 port exploded
// LDS bank conflicts 524K->11.3M and regressed; reverted).
// Round-8 delta (single, isolated): p3 B-reload interleave. r6 had {MMQ(q3); SBAR0; RD_BALL}
// -- the SBAR0 between them forbade overlapping the 8 b128 B-reloads with the MFMA stream,
// exposing their full port+issue time right before the barrier. Now each bn[jj][h] is consumed
// by its 2 MFMAs then reloaded from buf^1, pinned 1:1 via sched_group_barrier(MFMA,2 / DS_READ,1).
// Legal at any position in p3: buf^1 landed at p2's VMCNT4+ABAR; next overwrite of buf^1-B is
// behind next-p0's LGKM0+ABAR (unchanged invariant).
// Fused softmax: QK^T epilogue writes E=exp(S) bf16 + atomic fp32 row sums; PV normalizes.

typedef __attribute__((ext_vector_type(8))) short bf16x8;
typedef __attribute__((ext_vector_type(4))) float f32x4;
typedef __attribute__((ext_vector_type(8))) unsigned short u16x8;
typedef __attribute__((address_space(1))) const unsigned int gu32;
typedef __attribute__((address_space(3))) unsigned int lu32;

__device__ __forceinline__ unsigned short f2bf(float f) {
  union { float f; unsigned int u; } v; v.f = f;
  unsigned int r = v.u + 0x7fffu + ((v.u >> 16) & 1u);  // RNE
  return (unsigned short)(r >> 16);
}
__device__ __forceinline__ void cp16(const unsigned short* g, unsigned short* l) {
  __builtin_amdgcn_global_load_lds((gu32*)g, (lu32*)l, 16, 0, 0);
}

// ---- merged prep: x->xb bf16 (blocks 0..8191), W->Wt transpose (8192..8959), rowsum=0 (8960..9023)
__global__ __launch_bounds__(256) void prep(const float* __restrict__ x,
                                            unsigned short* __restrict__ xb,
                                            const float* __restrict__ W,
                                            unsigned short* __restrict__ Wt,
                                            float* __restrict__ rowsum) {
  __shared__ unsigned short tile[64][72];
  int bid = blockIdx.x, t = threadIdx.x;
  if (bid < 8192) {
    long i = ((long)bid * 256 + t) * 8;
    float4 a = *(const float4*)(x + i);
    float4 b = *(const float4*)(x + i + 4);
    u16x8 o;
    o[0] = f2bf(a.x); o[1] = f2bf(a.y); o[2] = f2bf(a.z); o[3] = f2bf(a.w);
    o[4] = f2bf(b.x); o[5] = f2bf(b.y); o[6] = f2bf(b.z); o[7] = f2bf(b.w);
    *(u16x8*)(xb + i) = o;
  } else if (bid < 8960) {
    int wb = bid - 8192;
    int fb = wb % 48, db = wb / 48;
#pragma unroll
    for (int it = 0; it < 4; it++) {
      int c = t + it * 256;
      int r = c >> 4, c4 = (c & 15) * 4;
      float4 v = *(const float4*)(W + (long)(db * 64 + r) * 3072 + fb * 64 + c4);
      tile[r][c4 + 0] = f2bf(v.x); tile[r][c4 + 1] = f2bf(v.y);
      tile[r][c4 + 2] = f2bf(v.z); tile[r][c4 + 3] = f2bf(v.w);
    }
    __syncthreads();
#pragma unroll
    for (int it = 0; it < 2; it++) {
      int c = t + it * 256;
      int r2 = c >> 3, k8 = (c & 7) * 8;
      u16x8 o;
#pragma unroll
      for (int j = 0; j < 8; j++) o[j] = tile[k8 + j][r2];
      *(u16x8*)(Wt + (long)(fb * 64 + r2) * 1024 + db * 64 + k8) = o;
    }
  } else {
    rowsum[(bid - 8960) * 256 + t] = 0.f;
  }
}

// ---- NT bf16 GEMM, 256x256 tile, BK=64, read-ahead 4-phase pipeline ----
// C[M,Ncols] = A[M,K]*B[Ncols,K]^T, K/64 a power of two (16 or 32 here).
// MODE 1: QKV epilogue: bf16(acc + bias[f]) -> Q,K row-major; V-blocks -> Vt[b][d][n] (LDS tr)
// MODE 3: E = bf16(exp(acc*scale)); fp32 row-sum partials atomicAdd'ed to rsum
// MODE 4: fp32 C = acc / rsum[row]  (PV -> out; fp32 stores are already full-line)
// SWZ: n-tile count; grid.x flattened: XCD-bijective remap then 4x4 super-tile decode.
template <int MODE, int SWZ>
__global__ __launch_bounds__(512, 2) void gemm256(
    const unsigned short* __restrict__ A, const unsigned short* __restrict__ B,
    float* __restrict__ C, const float* __restrict__ bias, int Ncols, int K, float scale,
    unsigned short* __restrict__ qp, unsigned short* __restrict__ kp,
    unsigned short* __restrict__ vp, float* __restrict__ rsum,
    long strA, long strB, long strC) {
  __shared__ __align__(16) unsigned short smem[4][256 * 64];  // [0..1]=A bufs, [2..3]=B bufs
  const int tid = threadIdx.x;
  const int lane = tid & 63, wave = tid >> 6;
  const int quad = lane >> 4, l16 = lane & 15;
  const int lr = lane >> 3, lc = lane & 7;
  const int bz = blockIdx.z;
  int mt, nt;
  {
    int bid = blockIdx.x;
    const int nx = gridDim.x;                  // multiple of 8
    bid = (bid & 7) * (nx >> 3) + (bid >> 3);  // XCD-contiguous bijective remap
    int w = bid & 15, st = bid >> 4;
    constexpr int NSUP = (SWZ >= 4) ? (SWZ / 4) : 1;
    mt = (st / NSUP) * 4 + (w >> 2);
    nt = (st % NSUP) * 4 + (w & 3);
  }
  const long m0 = (long)mt * 256;
  const int n0 = nt * 256;
  const int wm128 = (wave >> 2) * 128;   // wave's 128-row A stripe
  const int wn64 = (wave & 3) * 64;      // wave's 64-row B stripe
  const int NT = K >> 6, mask = NT - 1;

  const unsigned short* __restrict__ Ab = A + (long)bz * strA;
  const unsigned short* __restrict__ Bb = B + (long)bz * strB;

  // staging sub-units (8 KB = 1 cp16/thread each):
  //   A units: 0={rows 0-63}, 1={128-191}, 2={64-127}, 3={192-255}
  //   B units: 0={0-31,64-95}, 1={128-159,192-223}, 2={32-63,96-127}, 3={160-191,224-255}
  unsigned int aSrc[4], bSrc[4];
  int aOff[4], bOff[4];
  {
    const int auL[4] = {0, 128, 64, 192}, auH[4] = {32, 160, 96, 224};
    const int buL[4] = {0, 128, 32, 160}, buH[4] = {64, 192, 96, 224};
    const bool wlo = wave < 4;
    const int w8 = (wave & 3) * 8;
    const int sc = (lc ^ lr) * 8;  // pre-swizzled global chunk (LDS stays linear)
#pragma unroll
    for (int u = 0; u < 4; u++) {
      int ra = (wlo ? auL[u] : auH[u]) + w8 + lr;
      int rb = (wlo ? buL[u] : buH[u]) + w8 + lr;
      aSrc[u] = (unsigned int)(((int)m0 + ra) * K + sc);
      bSrc[u] = (unsigned int)((n0 + rb) * K + sc);
      aOff[u] = ra * 64 + lc * 8;
      bOff[u] = rb * 64 + lc * 8;
    }
  }

#define SA(u, bb, tt) cp16(Ab + aSrc[u] + (tt) * 64, &smem[bb][aOff[u]])
#define SB(u, bb, tt) cp16(Bb + bSrc[u] + (tt) * 64, &smem[2 + (bb)][bOff[u]])

  f32x4 acc[8][4];
  f32x4 zero = {0.f, 0.f, 0.f, 0.f};
#pragma unroll
  for (int i = 0; i < 8; i++)
#pragma unroll
    for (int j = 0; j < 4; j++) acc[i][j] = zero;
  bf16x8 am[2][2][2];  // [regbuf][frag][half] - A quarter double-buffer
  bf16x8 bn[4][2];     // [frag][half]         - full B stripe, 1 K-tile

  // ds-read: quarter q (2 m-frags) of buf bb into regbuf d
#define RD_AQ(d, bb, q)                                                                     \
  _Pragma("unroll") for (int ii = 0; ii < 2; ii++) {                                        \
    int row = wm128 + ((q) * 2 + ii) * 16 + l16;                                            \
    _Pragma("unroll") for (int h = 0; h < 2; h++)                                           \
      am[d][ii][h] = *(const bf16x8*)(&smem[bb][row * 64 + ((((h << 2) | quad)) ^ (row & 7)) * 8]); \
  }
  // ds-read: all 4 B frags of buf bb
#define RD_BALL(bb)                                                                         \
  _Pragma("unroll") for (int jj = 0; jj < 4; jj++) {                                        \
    int row = wn64 + jj * 16 + l16;                                                         \
    _Pragma("unroll") for (int h = 0; h < 2; h++)                                           \
      bn[jj][h] = *(const bf16x8*)(&smem[2 + (bb)][row * 64 + ((((h << 2) | quad)) ^ (row & 7)) * 8]); \
  }
  // MFMA: quarter q from regbuf d x all B frags (16 MFMA)
#define MMQ(q, d)                                                                           \
  _Pragma("unroll") for (int ii = 0; ii < 2; ii++)                                          \
    _Pragma("unroll") for (int jj = 0; jj < 4; jj++)                                        \
      _Pragma("unroll") for (int h = 0; h < 2; h++)                                         \
        acc[(q) * 2 + ii][jj] = __builtin_amdgcn_mfma_f32_16x16x32_bf16(                    \
            am[d][ii][h], bn[jj][h], acc[(q) * 2 + ii][jj], 0, 0, 0);
  // q3 variant: each bn[jj][h] has exactly 2 consumers in this phase -> consume both, then
  // reload that frag from buf nb. SGB pins {MFMA x2, DS_READ x1} repeating; reloads overlap
  // the MFMA stream instead of trailing it (r6's SBAR0 between MMQ and RD_BALL blocked this).
#define MMQ_BSWAP(q, d, nb)                                                                 \
  _Pragma("unroll") for (int jj = 0; jj < 4; jj++) {                                        \
    int row = wn64 + jj * 16 + l16;                                                         \
    _Pragma("unroll") for (int h = 0; h < 2; h++) {                                         \
      acc[(q) * 2 + 0][jj] = __builtin_amdgcn_mfma_f32_16x16x32_bf16(                       \
          am[d][0][h], bn[jj][h], acc[(q) * 2 + 0][jj], 0, 0, 0);                           \
      acc[(q) * 2 + 1][jj] = __builtin_amdgcn_mfma_f32_16x16x32_bf16(                       \
          am[d][1][h], bn[jj][h], acc[(q) * 2 + 1][jj], 0, 0, 0);                           \
      bn[jj][h] = *(const bf16x8*)(&smem[2 + (nb)][row * 64 + ((((h << 2) | quad)) ^ (row & 7)) * 8]); \
      __builtin_amdgcn_sched_group_barrier(0x008, 2, 0);                                    \
      __builtin_amdgcn_sched_group_barrier(0x100, 1, 0);                                    \
    }                                                                                       \
  }
#define ABAR asm volatile("s_barrier" ::: "memory")
#define LGKM0 asm volatile("s_waitcnt lgkmcnt(0)" ::: "memory")
#define VMCNT4 asm volatile("s_waitcnt vmcnt(4)" ::: "memory")
#define PRIO1 __builtin_amdgcn_s_setprio(1)
#define PRIO0 __builtin_amdgcn_s_setprio(0)
#define SBAR0 __builtin_amdgcn_sched_barrier(0)

  // Phase = {LGKM0; read-ahead; ABAR; stage; [SBAR0] MFMA [SBAR0]}. Same-phase read-ahead is
  // region-disjoint from the stage target. VMCNT4 @p2 pre-barrier: tile t+1 fully landed
  // before p3 reads buf^1. t2_ CLAMPED: tail junk re-reads the just-fetched last tile.
#define TILE(bb, tt)                                                                        \
  {                                                                                         \
    const int t2c_ = (tt) + 2;                                                              \
    const int t2_ = t2c_ > mask ? mask : t2c_;                                              \
    /* p0 */                                                                                \
    LGKM0; RD_AQ(1, bb, 1); ABAR;                                                           \
    SB(0, bb, t2_); SB(1, bb, t2_);                                                         \
    SBAR0; PRIO1; MMQ(0, 0); PRIO0; SBAR0;                                                  \
    /* p1 */                                                                                \
    LGKM0; RD_AQ(0, bb, 2); ABAR;                                                           \
    SA(0, bb, t2_); SA(1, bb, t2_);                                                         \
    SBAR0; PRIO1; MMQ(1, 1); PRIO0; SBAR0;                                                  \
    /* p2 */                                                                                \
    LGKM0; RD_AQ(1, bb, 3); VMCNT4; ABAR;                                                   \
    SB(2, bb, t2_); SB(3, bb, t2_);                                                         \
    SBAR0; PRIO1; MMQ(2, 0); PRIO0; SBAR0;                                                  \
    /* p3: MFMA q3 with interleaved B-reload from buf^1 (landed since p2) */                \
    LGKM0; RD_AQ(0, (bb) ^ 1, 0);                                                           \
    SBAR0; PRIO1; MMQ_BSWAP(3, 1, (bb) ^ 1); PRIO0; SBAR0;                                  \
    ABAR;                                                                                   \
    SA(2, bb, t2_); SA(3, bb, t2_);                                                         \
  }

  // prologue: stage tile0 + tile1 fully; land tile0 (all waves); read tile0's q0 + B
  SA(0, 0, 0); SA(1, 0, 0); SB(0, 0, 0); SB(1, 0, 0);
  SA(2, 0, 0); SA(3, 0, 0); SB(2, 0, 0); SB(3, 0, 0);
  SA(0, 1, 1); SA(1, 1, 1); SB(0, 1, 1); SB(1, 1, 1);
  SA(2, 1, 1); SA(3, 1, 1); SB(2, 1, 1); SB(3, 1, 1);
  asm volatile("s_waitcnt vmcnt(8)" ::: "memory");
  ABAR;
  RD_AQ(0, 0, 0);
  RD_BALL(0);

#pragma unroll 1
  for (int t = 0; t < NT; t += 2) {
    TILE(0, t);
    TILE(1, t + 1);
  }

  if (MODE == 1 || MODE == 3) {
    // ---- LDS-staged coalesced epilogue: 128KB LDS = one 256x256 bf16 C-tile ----
    asm volatile("s_waitcnt vmcnt(0)" ::: "memory");  // junk stages done writing LDS
    __syncthreads();
    unsigned short* Cs = &smem[0][0];  // row stride 512B, 16B-chunk XOR swizzle by (row&7)<<4
    if (MODE == 1) {
      float bv[4];
#pragma unroll
      for (int j = 0; j < 4; j++) bv[j] = bias[n0 + wn64 + j * 16 + l16];
      const bool isV = (n0 >= 2048);  // V-blocks dump TRANSPOSED: LDS[row=d][col=n]
#pragma unroll
      for (int i = 0; i < 8; i++)
#pragma unroll
        for (int r = 0; r < 4; r++) {
          int rw = wm128 + i * 16 + quad * 4 + r;
#pragma unroll
          for (int j = 0; j < 4; j++) {
            int cl = wn64 + j * 16 + l16;
            unsigned short hv = f2bf(acc[i][j][r] + bv[j]);
            int row = isV ? cl : rw, col = isV ? rw : cl;
            *(unsigned short*)((char*)Cs + ((row * 512 + col * 2) ^ ((row & 7) << 4))) = hv;
          }
        }
    } else {
      float* rs = rsum + bz * 2048;
#pragma unroll
      for (int i = 0; i < 8; i++)
#pragma unroll
        for (int r = 0; r < 4; r++) {
          int rw = wm128 + i * 16 + quad * 4 + r;
          float psum = 0.f;
#pragma unroll
          for (int j = 0; j < 4; j++) {
            float e = __expf(acc[i][j][r] * scale);
            psum += e;
            int col = wn64 + j * 16 + l16;
            *(unsigned short*)((char*)Cs + ((rw * 512 + col * 2) ^ ((rw & 7) << 4))) = f2bf(e);
          }
          psum += __shfl_xor(psum, 1);
          psum += __shfl_xor(psum, 2);
          psum += __shfl_xor(psum, 4);
          psum += __shfl_xor(psum, 8);
          if (l16 == 0) atomicAdd(rs + (m0 + rw), psum);
        }
    }
    __syncthreads();
    // write-out: 16 rounds x 256 rows, 512B contiguous per row (full lines, 16B/lane)
    const int rrow = tid >> 5, rchunk = tid & 31;
    unsigned short* dst;
    long rowstr, rowbase, colbase;
    if (MODE == 3) {
      dst = qp + (long)bz * strC;
      rowstr = Ncols; rowbase = m0; colbase = n0;
    } else if (n0 < 2048) {
      dst = (n0 < 1024) ? qp : kp;
      rowstr = 1024; rowbase = m0; colbase = n0 & 1023;
    } else {
      dst = vp;  // Vt[b][d][n]
      rowstr = 2048; rowbase = (m0 >> 11) * 1024 + (n0 - 2048); colbase = m0 & 2047;
    }
#pragma unroll
    for (int k = 0; k < 16; k++) {
      int row = k * 16 + rrow;
      u16x8 v = *(const u16x8*)((char*)Cs + ((row * 512 + rchunk * 16) ^ ((row & 7) << 4)));
      *(u16x8*)(dst + (rowbase + row) * rowstr + colbase + rchunk * 8) = v;
    }
  } else {
    float* Co = C + (long)bz * strC;
    const float* rs = rsum + bz * 2048;
#pragma unroll
    for (int i = 0; i < 8; i++)
#pragma unroll
      for (int r = 0; r < 4; r++) {
        long gm = m0 + wm128 + i * 16 + quad * 4 + r;
        float inv = 1.0f / rs[gm];
#pragma unroll
        for (int j = 0; j < 4; j++)
          Co[gm * Ncols + n0 + wn64 + j * 16 + l16] = acc[i][j][r] * inv;
      }
  }
  // drain in-flight junk prefetches + junk ds_reads before block exit
  asm volatile("s_waitcnt vmcnt(0) lgkmcnt(0)" ::: "memory");
#undef SA
#undef SB
#undef RD_AQ
#undef RD_BALL
#undef MMQ
#undef MMQ_BSWAP
#undef TILE
#undef ABAR
#undef LGKM0
#undef VMCNT4
#undef PRIO1
#undef PRIO0
#undef SBAR0
}

extern "C" void kernel_launch(void* const* d_in, const int* in_sizes, int n_in,
                              void* d_out, int out_size, void* d_ws, size_t ws_size,
                              hipStream_t stream) {
  const float* x = (const float*)d_in[0];
  const float* W = (const float*)d_in[1];
  const float* bq = (const float*)d_in[2];
  float* out = (float*)d_out;
  char* ws = (char*)d_ws;
  const long MB = 1L << 20;
  // Persistent: Q 0-32, K 32-64, Vt 64-96.
  // Phase A scratch: xb 96-128, Wt 128-134 (dead after QKV).
  // Phase B scratch: E bf16 96-160 (overlaps dead xb/Wt). rowsum 160 MB (64 KB).
  unsigned short* Q  = (unsigned short*)(ws);
  unsigned short* Kb = (unsigned short*)(ws + 32 * MB);
  unsigned short* Vt = (unsigned short*)(ws + 64 * MB);
  unsigned short* xb = (unsigned short*)(ws + 96 * MB);
  unsigned short* Wt = (unsigned short*)(ws + 128 * MB);
  unsigned short* E  = (unsigned short*)(ws + 96 * MB);
  float* rowsum      = (float*)(ws + 160 * MB);  // 8*2048 fp32 = 64 KB

  prep<<<9024, 256, 0, stream>>>(x, xb, W, Wt, rowsum);
  // QKV: [16384,3072] = xb[16384,1024] @ Wt[3072,1024]^T -> Q,K row-major; V -> Vt (LDS tr)
  gemm256<1, 12><<<dim3(768, 1, 1), 512, 0, stream>>>(xb, Wt, nullptr, bq, 3072, 1024, 1.0f,
                                                      Q, Kb, Vt, nullptr, 0, 0, 0);
  // E = exp((Q K^T) * scale) bf16 + rowsum atomics
  gemm256<3, 8><<<dim3(64, 1, 8), 512, 0, stream>>>(Q, Kb, nullptr, nullptr, 2048, 1024,
                                                    0.03125f, E, nullptr, nullptr, rowsum,
                                                    2048L * 1024, 2048L * 1024, 2048L * 2048);
  // out = (E @ Vt^T) / rowsum, fp32
  gemm256<4, 4><<<dim3(32, 1, 8), 512, 0, stream>>>(E, Vt, out, nullptr, 1024, 2048, 1.0f,
                                                    nullptr, nullptr, nullptr, rowsum,
                                                    2048L * 2048, 1024L * 2048, 2048L * 1024);
}

// Round 9
// 362.932 us; speedup vs baseline: 1.0617x; 1.0106x over previous
//
#include <hip/hip_runtime.h>
#include <hip/hip_bf16.h>

// Attention: x[8,2048,1024] fp32, W_qkv[1024,3072] fp32, b_qkv[3072] fp32 -> out[8,2048,1024] fp32
// 256x256-tile bf16 GEMMs. Round-9: ALL fragment ds_reads moved INSIDE the MFMA clusters,
// SGB-pinned {MFMA x4, DS_READ x1} (p3: x3) -- overlaps the CU-shared LDS read port
// (~2300 cy/tile) with the MFMA pipe (~2480 cy/tile) instead of serializing them (r8 wall
// 5465 cy/tile = read windows + MFMA windows back-to-back, barrier-locked). LGKM0 at phase
// END (reads issued ~400cy earlier -> drain cheap) preserves the stage-WAR invariant:
// stage of region R only after a barrier post-dating all waves' drained reads of R.
// Counted drain now vmcnt(6) at p2-end (tile t+1 fully landed before p3 reads buf^1;
// t+2's 6 stages ride on). One s_barrier per phase (4/tile, was 5).
// Fused softmax: QK^T epilogue writes E=exp(S) bf16 + atomic fp32 row sums; PV normalizes.

typedef __attribute__((ext_vector_type(8))) short bf16x8;
typedef __attribute__((ext_vector_type(4))) float f32x4;
typedef __attribute__((ext_vector_type(8))) unsigned short u16x8;
typedef __attribute__((address_space(1))) const unsigned int gu32;
typedef __attribute__((address_space(3))) unsigned int lu32;

__device__ __forceinline__ unsigned short f2bf(float f) {
  union { float f; unsigned int u; } v; v.f = f;
  unsigned int r = v.u + 0x7fffu + ((v.u >> 16) & 1u);  // RNE
  return (unsigned short)(r >> 16);
}
__device__ __forceinline__ void cp16(const unsigned short* g, unsigned short* l) {
  __builtin_amdgcn_global_load_lds((gu32*)g, (lu32*)l, 16, 0, 0);
}

// ---- merged prep: x->xb bf16 (blocks 0..8191), W->Wt transpose (8192..8959), rowsum=0 (8960..9023)
__global__ __launch_bounds__(256) void prep(const float* __restrict__ x,
                                            unsigned short* __restrict__ xb,
                                            const float* __restrict__ W,
                                            unsigned short* __restrict__ Wt,
                                            float* __restrict__ rowsum) {
  __shared__ unsigned short tile[64][72];
  int bid = blockIdx.x, t = threadIdx.x;
  if (bid < 8192) {
    long i = ((long)bid * 256 + t) * 8;
    float4 a = *(const float4*)(x + i);
    float4 b = *(const float4*)(x + i + 4);
    u16x8 o;
    o[0] = f2bf(a.x); o[1] = f2bf(a.y); o[2] = f2bf(a.z); o[3] = f2bf(a.w);
    o[4] = f2bf(b.x); o[5] = f2bf(b.y); o[6] = f2bf(b.z); o[7] = f2bf(b.w);
    *(u16x8*)(xb + i) = o;
  } else if (bid < 8960) {
    int wb = bid - 8192;
    int fb = wb % 48, db = wb / 48;
#pragma unroll
    for (int it = 0; it < 4; it++) {
      int c = t + it * 256;
      int r = c >> 4, c4 = (c & 15) * 4;
      float4 v = *(const float4*)(W + (long)(db * 64 + r) * 3072 + fb * 64 + c4);
      tile[r][c4 + 0] = f2bf(v.x); tile[r][c4 + 1] = f2bf(v.y);
      tile[r][c4 + 2] = f2bf(v.z); tile[r][c4 + 3] = f2bf(v.w);
    }
    __syncthreads();
#pragma unroll
    for (int it = 0; it < 2; it++) {
      int c = t + it * 256;
      int r2 = c >> 3, k8 = (c & 7) * 8;
      u16x8 o;
#pragma unroll
      for (int j = 0; j < 8; j++) o[j] = tile[k8 + j][r2];
      *(u16x8*)(Wt + (long)(fb * 64 + r2) * 1024 + db * 64 + k8) = o;
    }
  } else {
    rowsum[(bid - 8960) * 256 + t] = 0.f;
  }
}

// ---- NT bf16 GEMM, 256x256 tile, BK=64, interleaved read/MFMA 4-phase pipeline ----
// C[M,Ncols] = A[M,K]*B[Ncols,K]^T, K/64 a power of two (16 or 32 here).
// MODE 1: QKV epilogue: bf16(acc + bias[f]) -> Q,K row-major; V-blocks -> Vt[b][d][n] (LDS tr)
// MODE 3: E = bf16(exp(acc*scale)); fp32 row-sum partials atomicAdd'ed to rsum
// MODE 4: fp32 C = acc / rsum[row]  (PV -> out; fp32 stores are already full-line)
// SWZ: n-tile count; grid.x flattened: XCD-bijective remap then 4x4 super-tile decode.
template <int MODE, int SWZ>
__global__ __launch_bounds__(512, 2) void gemm256(
    const unsigned short* __restrict__ A, const unsigned short* __restrict__ B,
    float* __restrict__ C, const float* __restrict__ bias, int Ncols, int K, float scale,
    unsigned short* __restrict__ qp, unsigned short* __restrict__ kp,
    unsigned short* __restrict__ vp, float* __restrict__ rsum,
    long strA, long strB, long strC) {
  __shared__ __align__(16) unsigned short smem[4][256 * 64];  // [0..1]=A bufs, [2..3]=B bufs
  const int tid = threadIdx.x;
  const int lane = tid & 63, wave = tid >> 6;
  const int quad = lane >> 4, l16 = lane & 15;
  const int lr = lane >> 3, lc = lane & 7;
  const int bz = blockIdx.z;
  int mt, nt;
  {
    int bid = blockIdx.x;
    const int nx = gridDim.x;                  // multiple of 8
    bid = (bid & 7) * (nx >> 3) + (bid >> 3);  // XCD-contiguous bijective remap
    int w = bid & 15, st = bid >> 4;
    constexpr int NSUP = (SWZ >= 4) ? (SWZ / 4) : 1;
    mt = (st / NSUP) * 4 + (w >> 2);
    nt = (st % NSUP) * 4 + (w & 3);
  }
  const long m0 = (long)mt * 256;
  const int n0 = nt * 256;
  const int wm128 = (wave >> 2) * 128;   // wave's 128-row A stripe
  const int wn64 = (wave & 3) * 64;      // wave's 64-row B stripe
  const int NT = K >> 6, mask = NT - 1;

  const unsigned short* __restrict__ Ab = A + (long)bz * strA;
  const unsigned short* __restrict__ Bb = B + (long)bz * strB;

  // staging sub-units (8 KB = 1 cp16/thread each):
  //   A units: 0={rows 0-63}, 1={128-191}, 2={64-127}, 3={192-255}
  //   B units: 0={0-31,64-95}, 1={128-159,192-223}, 2={32-63,96-127}, 3={160-191,224-255}
  unsigned int aSrc[4], bSrc[4];
  int aOff[4], bOff[4];
  {
    const int auL[4] = {0, 128, 64, 192}, auH[4] = {32, 160, 96, 224};
    const int buL[4] = {0, 128, 32, 160}, buH[4] = {64, 192, 96, 224};
    const bool wlo = wave < 4;
    const int w8 = (wave & 3) * 8;
    const int sc = (lc ^ lr) * 8;  // pre-swizzled global chunk (LDS stays linear)
#pragma unroll
    for (int u = 0; u < 4; u++) {
      int ra = (wlo ? auL[u] : auH[u]) + w8 + lr;
      int rb = (wlo ? buL[u] : buH[u]) + w8 + lr;
      aSrc[u] = (unsigned int)(((int)m0 + ra) * K + sc);
      bSrc[u] = (unsigned int)((n0 + rb) * K + sc);
      aOff[u] = ra * 64 + lc * 8;
      bOff[u] = rb * 64 + lc * 8;
    }
  }

#define SA(u, bb, tt) cp16(Ab + aSrc[u] + (tt) * 64, &smem[bb][aOff[u]])
#define SB(u, bb, tt) cp16(Bb + bSrc[u] + (tt) * 64, &smem[2 + (bb)][bOff[u]])

  f32x4 acc[8][4];
  f32x4 zero = {0.f, 0.f, 0.f, 0.f};
#pragma unroll
  for (int i = 0; i < 8; i++)
#pragma unroll
    for (int j = 0; j < 4; j++) acc[i][j] = zero;
  bf16x8 am[2][2][2];  // [regbuf][frag][half] - A quarter double-buffer
  bf16x8 bn[4][2];     // [frag][half]         - full B stripe, 1 K-tile

  // prologue-only read macros
#define RD_AQ(d, bb, q)                                                                     \
  _Pragma("unroll") for (int ii = 0; ii < 2; ii++) {                                        \
    int row = wm128 + ((q) * 2 + ii) * 16 + l16;                                            \
    _Pragma("unroll") for (int h = 0; h < 2; h++)                                           \
      am[d][ii][h] = *(const bf16x8*)(&smem[bb][row * 64 + ((((h << 2) | quad)) ^ (row & 7)) * 8]); \
  }
#define RD_BALL(bb)                                                                         \
  _Pragma("unroll") for (int jj = 0; jj < 4; jj++) {                                        \
    int row = wn64 + jj * 16 + l16;                                                         \
    _Pragma("unroll") for (int h = 0; h < 2; h++)                                           \
      bn[jj][h] = *(const bf16x8*)(&smem[2 + (bb)][row * 64 + ((((h << 2) | quad)) ^ (row & 7)) * 8]); \
  }
  // Interleaved cluster (p0-p2): 16 MFMA consuming quarter q (am[d]) with the 4 ds_reads of
  // quarter qn (-> am[dn], buf bb) spread 1-per-4-MFMA via sched_group_barrier.
#define MMQ_INT(q, d, dn, qn, bb)                                                           \
  _Pragma("unroll") for (int jj = 0; jj < 4; jj++) {                                        \
    acc[(q) * 2 + 0][jj] = __builtin_amdgcn_mfma_f32_16x16x32_bf16(                         \
        am[d][0][0], bn[jj][0], acc[(q) * 2 + 0][jj], 0, 0, 0);                             \
    acc[(q) * 2 + 1][jj] = __builtin_amdgcn_mfma_f32_16x16x32_bf16(                         \
        am[d][1][0], bn[jj][0], acc[(q) * 2 + 1][jj], 0, 0, 0);                             \
    acc[(q) * 2 + 0][jj] = __builtin_amdgcn_mfma_f32_16x16x32_bf16(                         \
        am[d][0][1], bn[jj][1], acc[(q) * 2 + 0][jj], 0, 0, 0);                             \
    acc[(q) * 2 + 1][jj] = __builtin_amdgcn_mfma_f32_16x16x32_bf16(                         \
        am[d][1][1], bn[jj][1], acc[(q) * 2 + 1][jj], 0, 0, 0);                             \
    {                                                                                       \
      int ii_ = jj >> 1, h_ = jj & 1;                                                       \
      int row_ = wm128 + ((qn) * 2 + ii_) * 16 + l16;                                       \
      am[dn][ii_][h_] = *(const bf16x8*)(                                                   \
          &smem[bb][row_ * 64 + ((((h_ << 2) | quad)) ^ (row_ & 7)) * 8]);                  \
    }                                                                                       \
    __builtin_amdgcn_sched_group_barrier(0x008, 4, 0);                                      \
    __builtin_amdgcn_sched_group_barrier(0x100, 1, 0);                                      \
  }
  // p3 cluster: 16 MFMA consuming q3 (am[d]); per jj group reload bn[jj][0..1] and one q0'
  // fragment from buf nb (landed: vmcnt(6)+barrier at p2-end). {MFMA x4, DS x3} pinned.
#define MMQ_FIN(q, d, nb)                                                                   \
  _Pragma("unroll") for (int jj = 0; jj < 4; jj++) {                                        \
    acc[(q) * 2 + 0][jj] = __builtin_amdgcn_mfma_f32_16x16x32_bf16(                         \
        am[d][0][0], bn[jj][0], acc[(q) * 2 + 0][jj], 0, 0, 0);                             \
    acc[(q) * 2 + 1][jj] = __builtin_amdgcn_mfma_f32_16x16x32_bf16(                         \
        am[d][1][0], bn[jj][0], acc[(q) * 2 + 1][jj], 0, 0, 0);                             \
    acc[(q) * 2 + 0][jj] = __builtin_amdgcn_mfma_f32_16x16x32_bf16(                         \
        am[d][0][1], bn[jj][1], acc[(q) * 2 + 0][jj], 0, 0, 0);                             \
    acc[(q) * 2 + 1][jj] = __builtin_amdgcn_mfma_f32_16x16x32_bf16(                         \
        am[d][1][1], bn[jj][1], acc[(q) * 2 + 1][jj], 0, 0, 0);                             \
    {                                                                                       \
      int rowb_ = wn64 + jj * 16 + l16;                                                     \
      int rxb_ = rowb_ & 7;                                                                 \
      bn[jj][0] = *(const bf16x8*)(&smem[2 + (nb)][rowb_ * 64 + (quad ^ rxb_) * 8]);        \
      bn[jj][1] = *(const bf16x8*)(&smem[2 + (nb)][rowb_ * 64 + ((4 | quad) ^ rxb_) * 8]);  \
      int ii_ = jj >> 1, h_ = jj & 1;                                                       \
      int row_ = wm128 + ii_ * 16 + l16;                                                    \
      am[0][ii_][h_] = *(const bf16x8*)(                                                    \
          &smem[nb][row_ * 64 + ((((h_ << 2) | quad)) ^ (row_ & 7)) * 8]);                  \
    }                                                                                       \
    __builtin_amdgcn_sched_group_barrier(0x008, 4, 0);                                      \
    __builtin_amdgcn_sched_group_barrier(0x100, 3, 0);                                      \
  }
#define ABAR asm volatile("s_barrier" ::: "memory")
#define LGKM0 asm volatile("s_waitcnt lgkmcnt(0)" ::: "memory")
#define LGKM0VM6 asm volatile("s_waitcnt vmcnt(6) lgkmcnt(0)" ::: "memory")
#define PRIO1 __builtin_amdgcn_s_setprio(1)
#define PRIO0 __builtin_amdgcn_s_setprio(0)
#define SBAR0 __builtin_amdgcn_sched_barrier(0)

  // Phase = {ABAR; stage; [SBAR0] interleaved MFMA+reads [SBAR0]; LGKM0}.
  // Stage-WAR invariant per unit (unchanged from r8): SB01 regions' readers drained at
  // prev-p3-end; SA01's (q0: prev-p3, q1: p0) at p0-end; SB23's at prev-p3-end; SA23's
  // (q2: p1, q3: p2) at p2-end -- each before the ABAR preceding that stage.
  // LGKM0VM6 @p2-end: all of tile t+1 landed (6 newest outstanding = t+2's stages) before
  // p3's ABAR, after which p3 reads buf^1. t2_ CLAMPED: tail re-stages identical bytes.
#define TILE(bb, tt)                                                                        \
  {                                                                                         \
    const int t2c_ = (tt) + 2;                                                              \
    const int t2_ = t2c_ > mask ? mask : t2c_;                                              \
    /* p0: consume q0(am0) ; read q1->am1 ; stage B01(t+2) */                               \
    ABAR;                                                                                   \
    SB(0, bb, t2_); SB(1, bb, t2_);                                                         \
    SBAR0; PRIO1; MMQ_INT(0, 0, 1, 1, bb); PRIO0; SBAR0;                                    \
    LGKM0;                                                                                  \
    /* p1: consume q1 ; read q2->am0 ; stage A01(t+2) */                                    \
    ABAR;                                                                                   \
    SA(0, bb, t2_); SA(1, bb, t2_);                                                         \
    SBAR0; PRIO1; MMQ_INT(1, 1, 0, 2, bb); PRIO0; SBAR0;                                    \
    LGKM0;                                                                                  \
    /* p2: consume q2 ; read q3->am1 ; stage B23(t+2) ; counted drain */                    \
    ABAR;                                                                                   \
    SB(2, bb, t2_); SB(3, bb, t2_);                                                         \
    SBAR0; PRIO1; MMQ_INT(2, 0, 1, 3, bb); PRIO0; SBAR0;                                    \
    LGKM0VM6;                                                                               \
    /* p3: consume q3 ; read q0'+B' from buf^1 ; stage A23(t+2) */                          \
    ABAR;                                                                                   \
    SA(2, bb, t2_); SA(3, bb, t2_);                                                         \
    SBAR0; PRIO1; MMQ_FIN(3, 1, (bb) ^ 1); PRIO0; SBAR0;                                    \
    LGKM0;                                                                                  \
  }

  // prologue: stage tile0 + tile1 fully; land tile0 (all waves); read tile0's q0 + B
  SA(0, 0, 0); SA(1, 0, 0); SB(0, 0, 0); SB(1, 0, 0);
  SA(2, 0, 0); SA(3, 0, 0); SB(2, 0, 0); SB(3, 0, 0);
  SA(0, 1, 1); SA(1, 1, 1); SB(0, 1, 1); SB(1, 1, 1);
  SA(2, 1, 1); SA(3, 1, 1); SB(2, 1, 1); SB(3, 1, 1);
  asm volatile("s_waitcnt vmcnt(8)" ::: "memory");
  ABAR;
  RD_AQ(0, 0, 0);
  RD_BALL(0);
  LGKM0;

#pragma unroll 1
  for (int t = 0; t < NT; t += 2) {
    TILE(0, t);
    TILE(1, t + 1);
  }

  if (MODE == 1 || MODE == 3) {
    // ---- LDS-staged coalesced epilogue: 128KB LDS = one 256x256 bf16 C-tile ----
    asm volatile("s_waitcnt vmcnt(0)" ::: "memory");  // junk stages done writing LDS
    __syncthreads();
    unsigned short* Cs = &smem[0][0];  // row stride 512B, 16B-chunk XOR swizzle by (row&7)<<4
    if (MODE == 1) {
      float bv[4];
#pragma unroll
      for (int j = 0; j < 4; j++) bv[j] = bias[n0 + wn64 + j * 16 + l16];
      const bool isV = (n0 >= 2048);  // V-blocks dump TRANSPOSED: LDS[row=d][col=n]
#pragma unroll
      for (int i = 0; i < 8; i++)
#pragma unroll
        for (int r = 0; r < 4; r++) {
          int rw = wm128 + i * 16 + quad * 4 + r;
#pragma unroll
          for (int j = 0; j < 4; j++) {
            int cl = wn64 + j * 16 + l16;
            unsigned short hv = f2bf(acc[i][j][r] + bv[j]);
            int row = isV ? cl : rw, col = isV ? rw : cl;
            *(unsigned short*)((char*)Cs + ((row * 512 + col * 2) ^ ((row & 7) << 4))) = hv;
          }
        }
    } else {
      float* rs = rsum + bz * 2048;
#pragma unroll
      for (int i = 0; i < 8; i++)
#pragma unroll
        for (int r = 0; r < 4; r++) {
          int rw = wm128 + i * 16 + quad * 4 + r;
          float psum = 0.f;
#pragma unroll
          for (int j = 0; j < 4; j++) {
            float e = __expf(acc[i][j][r] * scale);
            psum += e;
            int col = wn64 + j * 16 + l16;
            *(unsigned short*)((char*)Cs + ((rw * 512 + col * 2) ^ ((rw & 7) << 4))) = f2bf(e);
          }
          psum += __shfl_xor(psum, 1);
          psum += __shfl_xor(psum, 2);
          psum += __shfl_xor(psum, 4);
          psum += __shfl_xor(psum, 8);
          if (l16 == 0) atomicAdd(rs + (m0 + rw), psum);
        }
    }
    __syncthreads();
    // write-out: 16 rounds x 256 rows, 512B contiguous per row (full lines, 16B/lane)
    const int rrow = tid >> 5, rchunk = tid & 31;
    unsigned short* dst;
    long rowstr, rowbase, colbase;
    if (MODE == 3) {
      dst = qp + (long)bz * strC;
      rowstr = Ncols; rowbase = m0; colbase = n0;
    } else if (n0 < 2048) {
      dst = (n0 < 1024) ? qp : kp;
      rowstr = 1024; rowbase = m0; colbase = n0 & 1023;
    } else {
      dst = vp;  // Vt[b][d][n]
      rowstr = 2048; rowbase = (m0 >> 11) * 1024 + (n0 - 2048); colbase = m0 & 2047;
    }
#pragma unroll
    for (int k = 0; k < 16; k++) {
      int row = k * 16 + rrow;
      u16x8 v = *(const u16x8*)((char*)Cs + ((row * 512 + rchunk * 16) ^ ((row & 7) << 4)));
      *(u16x8*)(dst + (rowbase + row) * rowstr + colbase + rchunk * 8) = v;
    }
  } else {
    float* Co = C + (long)bz * strC;
    const float* rs = rsum + bz * 2048;
#pragma unroll
    for (int i = 0; i < 8; i++)
#pragma unroll
      for (int r = 0; r < 4; r++) {
        long gm = m0 + wm128 + i * 16 + quad * 4 + r;
        float inv = 1.0f / rs[gm];
#pragma unroll
        for (int j = 0; j < 4; j++)
          Co[gm * Ncols + n0 + wn64 + j * 16 + l16] = acc[i][j][r] * inv;
      }
  }
  // drain in-flight junk prefetches + junk ds_reads before block exit
  asm volatile("s_waitcnt vmcnt(0) lgkmcnt(0)" ::: "memory");
#undef SA
#undef SB
#undef RD_AQ
#undef RD_BALL
#undef MMQ_INT
#undef MMQ_FIN
#undef TILE
#undef ABAR
#undef LGKM0
#undef LGKM0VM6
#undef PRIO1
#undef PRIO0
#undef SBAR0
}

extern "C" void kernel_launch(void* const* d_in, const int* in_sizes, int n_in,
                              void* d_out, int out_size, void* d_ws, size_t ws_size,
                              hipStream_t stream) {
  const float* x = (const float*)d_in[0];
  const float* W = (const float*)d_in[1];
  const float* bq = (const float*)d_in[2];
  float* out = (float*)d_out;
  char* ws = (char*)d_ws;
  const long MB = 1L << 20;
  // Persistent: Q 0-32, K 32-64, Vt 64-96.
  // Phase A scratch: xb 96-128, Wt 128-134 (dead after QKV).
  // Phase B scratch: E bf16 96-160 (overlaps dead xb/Wt). rowsum 160 MB (64 KB).
  unsigned short* Q  = (unsigned short*)(ws);
  unsigned short* Kb = (unsigned short*)(ws + 32 * MB);
  unsigned short* Vt = (unsigned short*)(ws + 64 * MB);
  unsigned short* xb = (unsigned short*)(ws + 96 * MB);
  unsigned short* Wt = (unsigned short*)(ws + 128 * MB);
  unsigned short* E  = (unsigned short*)(ws + 96 * MB);
  float* rowsum      = (float*)(ws + 160 * MB);  // 8*2048 fp32 = 64 KB

  prep<<<9024, 256, 0, stream>>>(x, xb, W, Wt, rowsum);
  // QKV: [16384,3072] = xb[16384,1024] @ Wt[3072,1024]^T -> Q,K row-major; V -> Vt (LDS tr)
  gemm256<1, 12><<<dim3(768, 1, 1), 512, 0, stream>>>(xb, Wt, nullptr, bq, 3072, 1024, 1.0f,
                                                      Q, Kb, Vt, nullptr, 0, 0, 0);
  // E = exp((Q K^T) * scale) bf16 + rowsum atomics
  gemm256<3, 8><<<dim3(64, 1, 8), 512, 0, stream>>>(Q, Kb, nullptr, nullptr, 2048, 1024,
                                                    0.03125f, E, nullptr, nullptr, rowsum,
                                                    2048L * 1024, 2048L * 1024, 2048L * 2048);
  // out = (E @ Vt^T) / rowsum, fp32
  gemm256<4, 4><<<dim3(32, 1, 8), 512, 0, stream>>>(E, Vt, out, nullptr, 1024, 2048, 1.0f,
                                                    nullptr, nullptr, nullptr, rowsum,
                                                    2048L * 2048, 1024L * 2048, 2048L * 1024);
}